// Round 5
// baseline (470.660 us; speedup 1.0000x reference)
//
#include <hip/hip_runtime.h>

// Problem constants (B=64 batches, n=64 nodes/batch, H=128, epg=2048 edges/batch)
#define NB 64
#define NPB 64
#define HD 128
#define EPB 2048
#define NNODE 4096     // NB*NPB
#define KK 52          // ceil(0.8*64)
#define NKOUT 3328     // NB*KK
#define NEG 0.01f

typedef __attribute__((ext_vector_type(8))) __bf16 bf16x8;
typedef __attribute__((ext_vector_type(16))) float floatx16;

__device__ __forceinline__ float lrelu(float v){ return v > 0.f ? v : NEG*v; }

// LDS layout for MFMA chunks: row pitch 40 bf16 (80B); XOR swizzle on 16B chunks (round-4 proven)
#define SW(r, ko) ((r)*40 + ((ko) ^ ((((r)>>3)&3) << 3)))

// exact 3-way bf16 split of 8 values + store to 3 LDS planes (fp32-faithful MFMA path)
__device__ __forceinline__ void split_store8(const float* vv, __bf16* P0, __bf16* P1, __bf16* P2, int addr){
  bf16x8 p1, p2, p3;
  #pragma unroll
  for (int j = 0; j < 8; j++){
    __bf16 b1 = (__bf16)vv[j];
    float r1 = vv[j] - (float)b1;
    __bf16 b2 = (__bf16)r1;
    float r2 = r1 - (float)b2;
    p1[j] = b1; p2[j] = b2; p3[j] = (__bf16)r2;
  }
  *(bf16x8*)(P0 + addr) = p1;
  *(bf16x8*)(P1 + addr) = p2;
  *(bf16x8*)(P2 + addr) = p3;
}

// 6-product bf16x6 MFMA accumulate (same product order as round 4 -> identical rounding)
__device__ __forceinline__ void mfma6(const __bf16* A0, const __bf16* A1, const __bf16* A2,
                                      const __bf16* B0, const __bf16* B1, const __bf16* B2,
                                      int aoff, int boff, floatx16* acc){
  bf16x8 a1 = *(const bf16x8*)(A0 + aoff);
  bf16x8 a2 = *(const bf16x8*)(A1 + aoff);
  bf16x8 a3 = *(const bf16x8*)(A2 + aoff);
  bf16x8 b1 = *(const bf16x8*)(B0 + boff);
  bf16x8 b2 = *(const bf16x8*)(B1 + boff);
  bf16x8 b3 = *(const bf16x8*)(B2 + boff);
  floatx16 c = *acc;
  c = __builtin_amdgcn_mfma_f32_32x32x16_bf16(a1,b1,c,0,0,0);
  c = __builtin_amdgcn_mfma_f32_32x32x16_bf16(a1,b2,c,0,0,0);
  c = __builtin_amdgcn_mfma_f32_32x32x16_bf16(a2,b1,c,0,0,0);
  c = __builtin_amdgcn_mfma_f32_32x32x16_bf16(a1,b3,c,0,0,0);
  c = __builtin_amdgcn_mfma_f32_32x32x16_bf16(a3,b1,c,0,0,0);
  c = __builtin_amdgcn_mfma_f32_32x32x16_bf16(a2,b2,c,0,0,0);
  *acc = c;
}

// ---------------- build A/M + xq = hop(hop(x)), fused per batch ----------------
__global__ __launch_bounds__(256) void k_build_hop(const int* __restrict__ ei, const float* __restrict__ w,
                                                   const float* __restrict__ x,
                                                   float* __restrict__ A_g, float* __restrict__ M_g,
                                                   float* __restrict__ xq){
  __shared__ float Ws[4096];
  __shared__ float Mc[4096];
  __shared__ float dv[64];
  __shared__ __align__(16) float V[8192];
  __shared__ __align__(16) float T[8192];
  int b = blockIdx.x, tid = threadIdx.x;
  for (int i = tid; i < 4096; i += 256){ Ws[i] = 0.f; Mc[i] = 0.f; }
  for (int i = tid*4; i < 8192; i += 1024)
    *(float4*)&V[i] = *(const float4*)(x + (size_t)b*8192 + i);
  __syncthreads();
  const int* r0 = ei + b*EPB;
  const int* c0 = ei + NB*EPB + b*EPB;
  const float* w0 = w + b*EPB;
  int base = b*NPB;
  for (int e = tid; e < EPB; e += 256){
    int r = r0[e] - base, c = c0[e] - base;
    atomicAdd(&Ws[r*64 + c], w0[e]);
    atomicAdd(&Mc[r*64 + c], 1.f);
  }
  if (tid < 64){ atomicAdd(&Ws[tid*64 + tid], 1.f); atomicAdd(&Mc[tid*64 + tid], 1.f); }
  __syncthreads();
  if (tid < 64){
    float d = 0.f;
    for (int r = 0; r < 64; r++) d += Ws[r*64 + tid];
    dv[tid] = d > 0.f ? rsqrtf(fmaxf(d, 1e-12f)) : 0.f;
  }
  __syncthreads();
  for (int i = tid; i < 4096; i += 256){
    int r = i >> 6, c = i & 63;
    float a = dv[r]*Ws[i]*dv[c];
    Ws[i] = a;
    A_g[b*4096 + i] = a;
    M_g[b*4096 + i] = Mc[i];
  }
  __syncthreads();
  int tc = (tid & 15)*4, tf = (tid >> 4)*8;
  float acc[4][8];
  #pragma unroll
  for (int i = 0; i < 4; i++)
    #pragma unroll
    for (int j = 0; j < 8; j++) acc[i][j] = 0.f;
  for (int r = 0; r < 64; r++){
    float4 a4 = *(const float4*)&Ws[r*64 + tc];
    float4 x0 = *(const float4*)&V[r*128 + tf];
    float4 x1 = *(const float4*)&V[r*128 + tf + 4];
    float a_[4] = {a4.x,a4.y,a4.z,a4.w};
    float v_[8] = {x0.x,x0.y,x0.z,x0.w,x1.x,x1.y,x1.z,x1.w};
    #pragma unroll
    for (int ci = 0; ci < 4; ci++)
      #pragma unroll
      for (int fj = 0; fj < 8; fj++) acc[ci][fj] += a_[ci]*v_[fj];
  }
  #pragma unroll
  for (int ci = 0; ci < 4; ci++){
    *(float4*)&T[(tc+ci)*128 + tf]     = make_float4(acc[ci][0],acc[ci][1],acc[ci][2],acc[ci][3]);
    *(float4*)&T[(tc+ci)*128 + tf + 4] = make_float4(acc[ci][4],acc[ci][5],acc[ci][6],acc[ci][7]);
  }
  __syncthreads();
  #pragma unroll
  for (int i = 0; i < 4; i++)
    #pragma unroll
    for (int j = 0; j < 8; j++) acc[i][j] = 0.f;
  for (int r = 0; r < 64; r++){
    float4 a4 = *(const float4*)&Ws[r*64 + tc];
    float4 x0 = *(const float4*)&T[r*128 + tf];
    float4 x1 = *(const float4*)&T[r*128 + tf + 4];
    float a_[4] = {a4.x,a4.y,a4.z,a4.w};
    float v_[8] = {x0.x,x0.y,x0.z,x0.w,x1.x,x1.y,x1.z,x1.w};
    #pragma unroll
    for (int ci = 0; ci < 4; ci++)
      #pragma unroll
      for (int fj = 0; fj < 8; fj++) acc[ci][fj] += a_[ci]*v_[fj];
  }
  #pragma unroll
  for (int ci = 0; ci < 4; ci++){
    *(float4*)(xq + (size_t)b*8192 + (tc+ci)*128 + tf)     = make_float4(acc[ci][0],acc[ci][1],acc[ci][2],acc[ci][3]);
    *(float4*)(xq + (size_t)b*8192 + (tc+ci)*128 + tf + 4) = make_float4(acc[ci][4],acc[ci][5],acc[ci][6],acc[ci][7]);
  }
}

// ---------------- fused attention: Wk @ -> foldedW1 @ -> W2 @ -> W3 . -> softmax ----------------
// grid (64, 2): block = (batch b, z). z=0: query per-node (qn); z=1: query tgt[b] broadcast.
__global__ __launch_bounds__(256) void k_attn(const float* __restrict__ kv, const float* __restrict__ qn,
                                              const float* __restrict__ tgt,
                                              const float* __restrict__ Wk, const float* __restrict__ W1,
                                              const float* __restrict__ W2, const float* __restrict__ W3,
                                              float* __restrict__ outF){
  __shared__ __align__(16) __bf16 As[3][64*40];    // A chunk planes (32-k)
  __shared__ __align__(16) __bf16 Bs[3][128*40];   // B chunk planes (32-k x 128-n)
  __shared__ __align__(16) float aB[64*132];       // 'a' buffer, later h2
  __shared__ __align__(16) float h1B[64*132];      // h1 half (per jh pass)
  __shared__ float lg[64];
  int b = blockIdx.x, z = blockIdx.y, tid = threadIdx.x;
  const float* Wkz = Wk + (size_t)z*16384;
  const float* W1z = W1 + (size_t)z*131072;
  const float* W2z = W2 + (size_t)z*32768;
  const float* W3z = W3 + (size_t)z*128;
  int sar = tid >> 2, sako = (tid & 3)*8;          // A staging: row, k-offset
  int bn  = tid & 127, bk = (tid >> 7)*16;         // B staging: col n, k-offset
  int wv_ = tid >> 6, L = tid & 63, m = L & 31, half = L >> 5;
  int rA  = 32*(wv_ & 1) + m;
  int tj0 = wv_ >> 1;                              // this wave's col tiles: tj0, tj0+2
  int rB0 = tj0*32 + m, rB1 = rB0 + 64;
  const float* kvrow = kv + ((size_t)b*64 + sar)*HD;
  const float* qrow  = (z == 0) ? qn + ((size_t)b*64 + sar)*HD : tgt + (size_t)b*HD;
  floatx16 accA, accB, acc3A, acc3B;
  #pragma unroll
  for (int i = 0; i < 16; i++){ accA[i]=0.f; accB[i]=0.f; }
  // ---- GEMM1: a = kv_b @ Wk (K=128, N=128) ----
  for (int k0 = 0; k0 < 128; k0 += 32){
    {
      float4 v0 = *(const float4*)(kvrow + k0 + sako);
      float4 v1 = *(const float4*)(kvrow + k0 + sako + 4);
      float vv[8] = {v0.x,v0.y,v0.z,v0.w,v1.x,v1.y,v1.z,v1.w};
      split_store8(vv, &As[0][0], &As[1][0], &As[2][0], SW(sar, sako));
    }
    {
      float vv[16];
      #pragma unroll
      for (int j = 0; j < 16; j++) vv[j] = Wkz[(size_t)(k0 + bk + j)*128 + bn];
      split_store8(vv,     &Bs[0][0], &Bs[1][0], &Bs[2][0], SW(bn, bk));
      split_store8(vv + 8, &Bs[0][0], &Bs[1][0], &Bs[2][0], SW(bn, bk + 8));
    }
    __syncthreads();
    #pragma unroll
    for (int kg = 0; kg < 2; kg++){
      int ko = kg*16 + half*8;
      mfma6(&As[0][0],&As[1][0],&As[2][0], &Bs[0][0],&Bs[1][0],&Bs[2][0], SW(rA,ko), SW(rB0,ko), &accA);
      mfma6(&As[0][0],&As[1][0],&As[2][0], &Bs[0][0],&Bs[1][0],&Bs[2][0], SW(rA,ko), SW(rB1,ko), &accB);
    }
    __syncthreads();
  }
  {
    int row0 = 32*(wv_ & 1) + 4*half;
    #pragma unroll
    for (int reg = 0; reg < 16; reg++){
      int row = row0 + (reg & 3) + 8*(reg >> 2);
      aB[row*132 + rB0] = accA[reg];
      aB[row*132 + rB1] = accB[reg];
    }
  }
  __syncthreads();
  // ---- GEMM2 (h @ W1fold, K=384) interleaved with GEMM3 (h1 @ W2) per N-half ----
  #pragma unroll
  for (int i = 0; i < 16; i++){ acc3A[i]=0.f; acc3B[i]=0.f; }
  for (int jh = 0; jh < 2; jh++){
    #pragma unroll
    for (int i = 0; i < 16; i++){ accA[i]=0.f; accB[i]=0.f; }
    for (int k0 = 0; k0 < 384; k0 += 32){
      int seg = k0 >> 7;
      int kl = (k0 & 127) + sako;
      {
        float vv[8];
        if (seg == 0){
          float4 v0 = *(const float4*)&aB[sar*132 + kl];
          float4 v1 = *(const float4*)&aB[sar*132 + kl + 4];
          vv[0]=v0.x; vv[1]=v0.y; vv[2]=v0.z; vv[3]=v0.w; vv[4]=v1.x; vv[5]=v1.y; vv[6]=v1.z; vv[7]=v1.w;
        } else if (seg == 1){
          float4 v0 = *(const float4*)(qrow + kl);
          float4 v1 = *(const float4*)(qrow + kl + 4);
          vv[0]=v0.x; vv[1]=v0.y; vv[2]=v0.z; vv[3]=v0.w; vv[4]=v1.x; vv[5]=v1.y; vv[6]=v1.z; vv[7]=v1.w;
        } else {
          float4 a0 = *(const float4*)&aB[sar*132 + kl];
          float4 a1 = *(const float4*)&aB[sar*132 + kl + 4];
          float4 q0 = *(const float4*)(qrow + kl);
          float4 q1 = *(const float4*)(qrow + kl + 4);
          vv[0]=a0.x*q0.x; vv[1]=a0.y*q0.y; vv[2]=a0.z*q0.z; vv[3]=a0.w*q0.w;
          vv[4]=a1.x*q1.x; vv[5]=a1.y*q1.y; vv[6]=a1.z*q1.z; vv[7]=a1.w*q1.w;
        }
        split_store8(vv, &As[0][0], &As[1][0], &As[2][0], SW(sar, sako));
      }
      {
        int colw = jh*128 + bn;
        float vv[16];
        #pragma unroll
        for (int j = 0; j < 16; j++){
          int kr = k0 + bk + j;
          const float* wp = W1z + (size_t)kr*256 + colw;
          float x_;
          if (kr < 128)       x_ = wp[0] + wp[256*256];   // W1a + W1c
          else if (kr < 256)  x_ = wp[0] - wp[128*256];   // W1b - W1c
          else                x_ = wp[128*256];           // W1d
          vv[j] = x_;
        }
        split_store8(vv,     &Bs[0][0], &Bs[1][0], &Bs[2][0], SW(bn, bk));
        split_store8(vv + 8, &Bs[0][0], &Bs[1][0], &Bs[2][0], SW(bn, bk + 8));
      }
      __syncthreads();
      #pragma unroll
      for (int kg = 0; kg < 2; kg++){
        int ko = kg*16 + half*8;
        mfma6(&As[0][0],&As[1][0],&As[2][0], &Bs[0][0],&Bs[1][0],&Bs[2][0], SW(rA,ko), SW(rB0,ko), &accA);
        mfma6(&As[0][0],&As[1][0],&As[2][0], &Bs[0][0],&Bs[1][0],&Bs[2][0], SW(rA,ko), SW(rB1,ko), &accB);
      }
      __syncthreads();
    }
    {
      int row0 = 32*(wv_ & 1) + 4*half;
      #pragma unroll
      for (int reg = 0; reg < 16; reg++){
        int row = row0 + (reg & 3) + 8*(reg >> 2);
        h1B[row*132 + rB0] = lrelu(accA[reg]);
        h1B[row*132 + rB1] = lrelu(accB[reg]);
      }
    }
    __syncthreads();
    // GEMM3 partial over this K-half (rows jh*128.. of W2)
    for (int k0 = 0; k0 < 128; k0 += 32){
      {
        float4 v0 = *(const float4*)&h1B[sar*132 + k0 + sako];
        float4 v1 = *(const float4*)&h1B[sar*132 + k0 + sako + 4];
        float vv[8] = {v0.x,v0.y,v0.z,v0.w,v1.x,v1.y,v1.z,v1.w};
        split_store8(vv, &As[0][0], &As[1][0], &As[2][0], SW(sar, sako));
      }
      {
        float vv[16];
        #pragma unroll
        for (int j = 0; j < 16; j++) vv[j] = W2z[(size_t)(jh*128 + k0 + bk + j)*128 + bn];
        split_store8(vv,     &Bs[0][0], &Bs[1][0], &Bs[2][0], SW(bn, bk));
        split_store8(vv + 8, &Bs[0][0], &Bs[1][0], &Bs[2][0], SW(bn, bk + 8));
      }
      __syncthreads();
      #pragma unroll
      for (int kg = 0; kg < 2; kg++){
        int ko = kg*16 + half*8;
        mfma6(&As[0][0],&As[1][0],&As[2][0], &Bs[0][0],&Bs[1][0],&Bs[2][0], SW(rA,ko), SW(rB0,ko), &acc3A);
        mfma6(&As[0][0],&As[1][0],&As[2][0], &Bs[0][0],&Bs[1][0],&Bs[2][0], SW(rA,ko), SW(rB1,ko), &acc3B);
      }
      __syncthreads();
    }
  }
  // h2 -> aB (reuse)
  {
    int row0 = 32*(wv_ & 1) + 4*half;
    #pragma unroll
    for (int reg = 0; reg < 16; reg++){
      int row = row0 + (reg & 3) + 8*(reg >> 2);
      aB[row*132 + rB0] = lrelu(acc3A[reg]);
      aB[row*132 + rB1] = lrelu(acc3B[reg]);
    }
  }
  __syncthreads();
  // W3 dot + leaky, then per-batch softmax
  {
    float w0 = W3z[L], w1 = W3z[L + 64];
    #pragma unroll 4
    for (int i = 0; i < 16; i++){
      int row = wv_*16 + i;
      float v = aB[row*132 + L]*w0 + aB[row*132 + 64 + L]*w1;
      #pragma unroll
      for (int off = 32; off; off >>= 1) v += __shfl_down(v, off);
      if (L == 0) lg[row] = lrelu(v);
    }
  }
  __syncthreads();
  if (tid < 64){
    float l = lg[tid];
    float mx = l;
    #pragma unroll
    for (int off = 32; off; off >>= 1) mx = fmaxf(mx, __shfl_xor(mx, off));
    float e = expf(l - mx);
    float s = e;
    #pragma unroll
    for (int off = 32; off; off >>= 1) s += __shfl_xor(s, off);
    outF[z*NNODE + b*64 + tid] = e/s;
  }
}

// ---------------- edge softmax (multiplicity-weighted) + S + agg ----------------
__global__ __launch_bounds__(256) void k_edge(const float* __restrict__ M_g, const float* __restrict__ fb,
                                              const float* __restrict__ x, float* __restrict__ S_g,
                                              float* __restrict__ agg){
  __shared__ __align__(16) float Mc[4096];
  __shared__ __align__(16) float xb[8192];
  __shared__ float f1s[64], f2s[64];
  int b = blockIdx.x, tid = threadIdx.x;
  for (int i = tid; i < 4096; i += 256) Mc[i] = M_g[b*4096 + i];
  for (int i = tid*4; i < 8192; i += 1024)
    *(float4*)&xb[i] = *(const float4*)(x + (size_t)b*8192 + i);
  if (tid < 64) f1s[tid] = fb[b*64 + tid];
  else if (tid < 128) f2s[tid - 64] = fb[NNODE + b*64 + (tid - 64)];
  __syncthreads();
  int c = tid >> 2, sub = tid & 3;
  float m = -1e30f;
  for (int r = sub; r < 64; r += 4)
    if (Mc[r*64 + c] > 0.f) m = fmaxf(m, lrelu(f1s[c] + f2s[r]));
  m = fmaxf(m, __shfl_xor(m, 1));
  m = fmaxf(m, __shfl_xor(m, 2));
  float s = 0.f;
  for (int r = sub; r < 64; r += 4){
    float mc = Mc[r*64 + c];
    if (mc > 0.f) s += mc*expf(lrelu(f1s[c] + f2s[r]) - m);
  }
  s += __shfl_xor(s, 1);
  s += __shfl_xor(s, 2);
  for (int r = sub; r < 64; r += 4){
    float mc = Mc[r*64 + c];
    float v = 0.f;
    if (mc > 0.f) v = mc*expf(lrelu(f1s[c] + f2s[r]) - m)/s;
    Mc[r*64 + c] = v;
  }
  __syncthreads();
  for (int i = tid; i < 4096; i += 256) S_g[b*4096 + i] = Mc[i];
  int tc = (tid & 15)*4, tf = (tid >> 4)*8;
  float acc[4][8];
  #pragma unroll
  for (int i = 0; i < 4; i++)
    #pragma unroll
    for (int j = 0; j < 8; j++) acc[i][j] = 0.f;
  for (int r = 0; r < 64; r++){
    float4 e4 = *(const float4*)&Mc[r*64 + tc];
    float4 x0 = *(const float4*)&xb[r*128 + tf];
    float4 x1 = *(const float4*)&xb[r*128 + tf + 4];
    float e_[4] = {e4.x,e4.y,e4.z,e4.w};
    float x_[8] = {x0.x,x0.y,x0.z,x0.w,x1.x,x1.y,x1.z,x1.w};
    #pragma unroll
    for (int ci = 0; ci < 4; ci++)
      #pragma unroll
      for (int fj = 0; fj < 8; fj++) acc[ci][fj] += e_[ci]*x_[fj];
  }
  #pragma unroll
  for (int ci = 0; ci < 4; ci++){
    *(float4*)(agg + (size_t)b*8192 + (tc+ci)*128 + tf)     = make_float4(acc[ci][0],acc[ci][1],acc[ci][2],acc[ci][3]);
    *(float4*)(agg + (size_t)b*8192 + (tc+ci)*128 + tf + 4) = make_float4(acc[ci][4],acc[ci][5],acc[ci][6],acc[ci][7]);
  }
}

// ---------------- lin GEMM (2 heads) + x_c + hop2(x_c), fused per batch ----------------
__global__ __launch_bounds__(256) void k_lin_xc_hop(const float* __restrict__ aggb, const float* __restrict__ x,
                                                    const float* __restrict__ linW, const float* __restrict__ A_g,
                                                    float* __restrict__ xc, float* __restrict__ xq2){
  __shared__ __align__(16) __bf16 As[3][64*40];
  __shared__ __align__(16) __bf16 Bs[3][128*40];
  __shared__ __align__(16) float Ab[4096];
  __shared__ __align__(16) float xcV[8192];
  __shared__ __align__(16) float T[8192];
  int b = blockIdx.x, tid = threadIdx.x;
  int sar = tid >> 2, sako = (tid & 3)*8;
  int bn  = tid & 127, bk = (tid >> 7)*16;
  int wv_ = tid >> 6, L = tid & 63, m = L & 31, half = L >> 5;
  int rA  = 32*(wv_ & 1) + m;
  int tj0 = wv_ >> 1;
  int rB0 = tj0*32 + m, rB1 = rB0 + 64;
  const float* arow = aggb + ((size_t)b*64 + sar)*HD;
  floatx16 acc0A, acc0B, acc1A, acc1B;
  #pragma unroll
  for (int i = 0; i < 16; i++){ acc0A[i]=0.f; acc0B[i]=0.f; acc1A[i]=0.f; acc1B[i]=0.f; }
  for (int h = 0; h < 2; h++){
    for (int k0 = 0; k0 < 128; k0 += 32){
      {
        float4 v0 = *(const float4*)(arow + k0 + sako);
        float4 v1 = *(const float4*)(arow + k0 + sako + 4);
        float vv[8] = {v0.x,v0.y,v0.z,v0.w,v1.x,v1.y,v1.z,v1.w};
        split_store8(vv, &As[0][0], &As[1][0], &As[2][0], SW(sar, sako));
      }
      {
        float vv[16];
        #pragma unroll
        for (int j = 0; j < 16; j++) vv[j] = linW[(size_t)h*16384 + (size_t)(k0 + bk + j)*128 + bn];
        split_store8(vv,     &Bs[0][0], &Bs[1][0], &Bs[2][0], SW(bn, bk));
        split_store8(vv + 8, &Bs[0][0], &Bs[1][0], &Bs[2][0], SW(bn, bk + 8));
      }
      __syncthreads();
      #pragma unroll
      for (int kg = 0; kg < 2; kg++){
        int ko = kg*16 + half*8;
        if (h == 0){
          mfma6(&As[0][0],&As[1][0],&As[2][0], &Bs[0][0],&Bs[1][0],&Bs[2][0], SW(rA,ko), SW(rB0,ko), &acc0A);
          mfma6(&As[0][0],&As[1][0],&As[2][0], &Bs[0][0],&Bs[1][0],&Bs[2][0], SW(rA,ko), SW(rB1,ko), &acc0B);
        } else {
          mfma6(&As[0][0],&As[1][0],&As[2][0], &Bs[0][0],&Bs[1][0],&Bs[2][0], SW(rA,ko), SW(rB0,ko), &acc1A);
          mfma6(&As[0][0],&As[1][0],&As[2][0], &Bs[0][0],&Bs[1][0],&Bs[2][0], SW(rA,ko), SW(rB1,ko), &acc1B);
        }
      }
      __syncthreads();
    }
  }
  // x_c epilogue
  {
    int row0 = 32*(wv_ & 1) + 4*half;
    #pragma unroll
    for (int reg = 0; reg < 16; reg++){
      int row = row0 + (reg & 3) + 8*(reg >> 2);
      float xv0 = x[((size_t)b*64 + row)*HD + rB0];
      float v0 = 0.5f*(lrelu(xv0 + acc0A[reg]) + lrelu(xv0 + acc1A[reg]));
      xcV[row*128 + rB0] = v0;
      xc[(size_t)b*8192 + row*128 + rB0] = v0;
      float xv1 = x[((size_t)b*64 + row)*HD + rB1];
      float v1 = 0.5f*(lrelu(xv1 + acc0B[reg]) + lrelu(xv1 + acc1B[reg]));
      xcV[row*128 + rB1] = v1;
      xc[(size_t)b*8192 + row*128 + rB1] = v1;
    }
  }
  for (int i = tid*4; i < 4096; i += 1024)
    *(float4*)&Ab[i] = *(const float4*)(A_g + b*4096 + i);
  __syncthreads();
  // hop2(x_c)
  int tc = (tid & 15)*4, tf = (tid >> 4)*8;
  float acc[4][8];
  #pragma unroll
  for (int i = 0; i < 4; i++)
    #pragma unroll
    for (int j = 0; j < 8; j++) acc[i][j] = 0.f;
  for (int r = 0; r < 64; r++){
    float4 a4 = *(const float4*)&Ab[r*64 + tc];
    float4 x0 = *(const float4*)&xcV[r*128 + tf];
    float4 x1 = *(const float4*)&xcV[r*128 + tf + 4];
    float a_[4] = {a4.x,a4.y,a4.z,a4.w};
    float v_[8] = {x0.x,x0.y,x0.z,x0.w,x1.x,x1.y,x1.z,x1.w};
    #pragma unroll
    for (int ci = 0; ci < 4; ci++)
      #pragma unroll
      for (int fj = 0; fj < 8; fj++) acc[ci][fj] += a_[ci]*v_[fj];
  }
  #pragma unroll
  for (int ci = 0; ci < 4; ci++){
    *(float4*)&T[(tc+ci)*128 + tf]     = make_float4(acc[ci][0],acc[ci][1],acc[ci][2],acc[ci][3]);
    *(float4*)&T[(tc+ci)*128 + tf + 4] = make_float4(acc[ci][4],acc[ci][5],acc[ci][6],acc[ci][7]);
  }
  __syncthreads();
  #pragma unroll
  for (int i = 0; i < 4; i++)
    #pragma unroll
    for (int j = 0; j < 8; j++) acc[i][j] = 0.f;
  for (int r = 0; r < 64; r++){
    float4 a4 = *(const float4*)&Ab[r*64 + tc];
    float4 x0 = *(const float4*)&T[r*128 + tf];
    float4 x1 = *(const float4*)&T[r*128 + tf + 4];
    float a_[4] = {a4.x,a4.y,a4.z,a4.w};
    float v_[8] = {x0.x,x0.y,x0.z,x0.w,x1.x,x1.y,x1.z,x1.w};
    #pragma unroll
    for (int ci = 0; ci < 4; ci++)
      #pragma unroll
      for (int fj = 0; fj < 8; fj++) acc[ci][fj] += a_[ci]*v_[fj];
  }
  #pragma unroll
  for (int ci = 0; ci < 4; ci++){
    *(float4*)(xq2 + (size_t)b*8192 + (tc+ci)*128 + tf)     = make_float4(acc[ci][0],acc[ci][1],acc[ci][2],acc[ci][3]);
    *(float4*)(xq2 + (size_t)b*8192 + (tc+ci)*128 + tf + 4) = make_float4(acc[ci][4],acc[ci][5],acc[ci][6],acc[ci][7]);
  }
}

// ---------------- fused: cluster-score softmax + exact top-52 + x_out gather ----------------
__global__ __launch_bounds__(256) void k_pool(const float* __restrict__ gb, const float* __restrict__ x,
                                              int* __restrict__ pidx, float* __restrict__ outB,
                                              float* __restrict__ outP, float* __restrict__ outX){
  int b = blockIdx.x, tid = threadIdx.x;
  __shared__ int pi[KK];
  __shared__ float pv[KK];
  if (tid < 64){
    float l = gb[b*64 + tid] + gb[NNODE + b*64 + tid];
    float m = l;
    #pragma unroll
    for (int off = 32; off; off >>= 1) m = fmaxf(m, __shfl_xor(m, off));
    float e = expf(l - m);
    float sm = e;
    #pragma unroll
    for (int off = 32; off; off >>= 1) sm += __shfl_xor(sm, off);
    float s = e/sm;
    int lane = tid;
    for (int t = 0; t < KK; t++){
      float v = s; int idx = lane;
      #pragma unroll
      for (int off = 32; off; off >>= 1){
        float ov = __shfl_xor(v, off); int oi = __shfl_xor(idx, off);
        if (ov > v || (ov == v && oi < idx)){ v = ov; idx = oi; }
      }
      if (lane == 0){
        pi[t] = idx; pv[t] = v;
        pidx[b*KK + t] = idx;
        outB[b*KK + t] = (float)b;
        outP[b*KK + t] = (float)(b*64 + idx);
      }
      if (lane == idx) s = -1e30f;
    }
  }
  __syncthreads();
  for (int o = tid*4; o < KK*HD; o += 1024){
    int j = o >> 7, f = o & 127;
    float4 xv = *(const float4*)(x + ((size_t)b*64 + pi[j])*HD + f);
    float sv = pv[j];
    *(float4*)(outX + (size_t)b*KK*HD + o) = make_float4(xv.x*sv, xv.y*sv, xv.z*sv, xv.w*sv);
  }
}

// ---------------- per-batch A2 rows: S_p^T (A S_p), diag=1, full-row writes incl zeros ----------------
__global__ __launch_bounds__(256) void k_A2(const float* __restrict__ A_g, const float* __restrict__ S_g,
                                            const int* __restrict__ pidx, float* __restrict__ outA2){
  __shared__ __align__(16) float At[64*68];
  __shared__ __align__(16) float Sp[64*56];
  __shared__ __align__(16) float T[64*56];
  __shared__ __align__(16) float C2[KK*56];
  __shared__ int pc[KK];
  int b = blockIdx.x, tid = threadIdx.x;
  if (tid < KK) pc[tid] = pidx[b*KK + tid];
  __syncthreads();
  for (int idx = tid; idx < 4096; idx += 256){
    int i = idx >> 6, k = idx & 63;
    At[k*68 + i] = A_g[b*4096 + idx];
  }
  for (int idx = tid; idx < 4096; idx += 256){
    int k = idx >> 6, t = idx & 63;
    if (t < 56) Sp[k*56 + t] = (t < KK) ? S_g[b*4096 + k*64 + pc[t]] : 0.f;
  }
  __syncthreads();
  if (tid < 224){
    int i0 = (tid/14)*4, t0 = (tid % 14)*4;
    float acc[4][4];
    #pragma unroll
    for (int a = 0; a < 4; a++)
      #pragma unroll
      for (int c = 0; c < 4; c++) acc[a][c] = 0.f;
    for (int k = 0; k < 64; k++){
      float4 a4 = *(const float4*)&At[k*68 + i0];
      float4 s4 = *(const float4*)&Sp[k*56 + t0];
      float a_[4] = {a4.x,a4.y,a4.z,a4.w};
      float s_[4] = {s4.x,s4.y,s4.z,s4.w};
      #pragma unroll
      for (int ii = 0; ii < 4; ii++)
        #pragma unroll
        for (int tt = 0; tt < 4; tt++) acc[ii][tt] += a_[ii]*s_[tt];
    }
    #pragma unroll
    for (int ii = 0; ii < 4; ii++)
      *(float4*)&T[(i0+ii)*56 + t0] = make_float4(acc[ii][0],acc[ii][1],acc[ii][2],acc[ii][3]);
  }
  __syncthreads();
  if (tid < 169){
    int a0 = (tid/13)*4, t0 = (tid % 13)*4;
    float acc[4][4];
    #pragma unroll
    for (int a = 0; a < 4; a++)
      #pragma unroll
      for (int c = 0; c < 4; c++) acc[a][c] = 0.f;
    for (int i = 0; i < 64; i++){
      float4 s4 = *(const float4*)&Sp[i*56 + a0];
      float4 t4 = *(const float4*)&T[i*56 + t0];
      float s_[4] = {s4.x,s4.y,s4.z,s4.w};
      float t_[4] = {t4.x,t4.y,t4.z,t4.w};
      #pragma unroll
      for (int aa = 0; aa < 4; aa++)
        #pragma unroll
        for (int tt = 0; tt < 4; tt++) acc[aa][tt] += s_[aa]*t_[tt];
    }
    #pragma unroll
    for (int aa = 0; aa < 4; aa++)
      #pragma unroll
      for (int tt = 0; tt < 4; tt++){
        int a = a0 + aa, t = t0 + tt;
        C2[a*56 + t] = (a == t) ? 1.f : acc[aa][tt];
      }
  }
  __syncthreads();
  // write full 52 rows (3328 cols each): zeros outside our 13 float4 slots
  for (int o = tid; o < KK*832; o += 256){
    int a = o/832, c4 = o - a*832;
    int rel = c4 - b*13;
    float4 val;
    if (rel >= 0 && rel < 13){
      int t0 = rel*4;
      val = make_float4(C2[a*56 + t0], C2[a*56 + t0 + 1], C2[a*56 + t0 + 2], C2[a*56 + t0 + 3]);
    } else {
      val = make_float4(0.f, 0.f, 0.f, 0.f);
    }
    *(float4*)(outA2 + (size_t)(b*KK + a)*NKOUT + c4*4) = val;
  }
}

extern "C" void kernel_launch(void* const* d_in, const int* in_sizes, int n_in,
                              void* d_out, int out_size, void* d_ws, size_t ws_size,
                              hipStream_t stream){
  const float* x    = (const float*)d_in[0];
  const int*   ei   = (const int*)d_in[1];
  const float* ew   = (const float*)d_in[2];
  const float* tgt  = (const float*)d_in[3];
  const float* Wk   = (const float*)d_in[5];
  const float* W1   = (const float*)d_in[6];
  const float* W2   = (const float*)d_in[7];
  const float* W3   = (const float*)d_in[8];
  const float* linW = (const float*)d_in[9];
  float* out = (float*)d_out;

  float* wf    = (float*)d_ws;
  float* A_g   = wf;                   // 262144
  float* M_g   = A_g + 262144;
  float* S_g   = M_g + 262144;
  float* xq    = S_g + 262144;         // 524288
  float* xq2   = xq + 524288;
  float* aggb  = xq2 + 524288;
  float* xcb   = aggb + 524288;
  float* fb    = xcb + 524288;         // 2 x 4096
  float* gb    = fb + 8192;            // 2 x 4096
  int*   pidx  = (int*)(gb + 8192);    // NKOUT

  float* outX  = out;                          // 3328 x 128
  float* outA2 = out + 425984;                 // 3328 x 3328
  float* outB  = out + 425984 + 11075584;      // 3328
  float* outP  = outB + NKOUT;                 // 3328

  // 1. build A/M + xq = hop(hop(x))
  k_build_hop<<<dim3(64), dim3(256), 0, stream>>>(ei, ew, x, A_g, M_g, xq);
  // 2. attention pair f (kv=x; q: z0=xq, z1=target) -> fb
  k_attn<<<dim3(64,2), dim3(256), 0, stream>>>(x, xq, tgt, Wk, W1, W2, W3, fb);
  // 3. edge softmax -> S, agg
  k_edge<<<dim3(64), dim3(256), 0, stream>>>(M_g, fb, x, S_g, aggb);
  // 4. lin GEMM + x_c + xq2 = hop(hop(x_c))
  k_lin_xc_hop<<<dim3(64), dim3(256), 0, stream>>>(aggb, x, linW, A_g, xcb, xq2);
  // 5. attention pair g (kv=x_c; q: z0=xq2, z1=target) -> gb
  k_attn<<<dim3(64,2), dim3(256), 0, stream>>>(xcb, xq2, tgt,
                                               Wk + 2*16384, W1 + 2*131072, W2 + 2*32768, W3 + 2*128, gb);
  // 6. cluster score + top-k + x_out
  k_pool<<<dim3(64), dim3(256), 0, stream>>>(gb, x, pidx, outB, outP, outX);
  // 7. A2 rows (incl. zero fill)
  k_A2<<<dim3(64), dim3(256), 0, stream>>>(A_g, S_g, pidx, outA2);
}